// Round 13
// baseline (113.810 us; speedup 1.0000x reference)
//
#include <hip/hip_runtime.h>
#include <math.h>

// Canny-style Sobel NMS + double threshold on 4096x4096 f32.
// Reference's direction predicate b1 is vacuously true -> NMS is horizontal.
//
// R13: R12's latency fixes (wave-sized blocks, sched_barrier-pinned up-front
// loads) + R11's byte savings (ROWS=16 -> read amp 1.125x, 2.19 mem insts/
// row). R11 failed only because the compiler sank the 18 loads (VGPR=72
// proved it) and 256-thread blocks made residency lumpy; both are fixed here.
// 19 full-width loads in flight per wave, 4096 wave-blocks (16 waves/CU --
// the residency at which R8 already hit the plateau's best time).
// Math identical to the verified absmax-0.0 path: exact squared-domain NMS +
// double threshold with integer hazard net -> rare sqrtf reference fallback.

constexpr int Wd = 4096;
constexpr int Ht = 4096;
constexpr int ROWS = 16;

typedef float f4 __attribute__((ext_vector_type(4)));
typedef float f2 __attribute__((ext_vector_type(2)));

__global__ __launch_bounds__(64) void canny_kernel(const float* __restrict__ x,
                                                   float* __restrict__ out) {
    const int lane = threadIdx.x;                    // block == wave
    const int wc   = blockIdx.x;                     // 256-col band, 0..15
    const int cbase = wc * 256;
    const int c     = cbase + lane * 4;              // lane's first col
    const int r0    = blockIdx.y * ROWS;             // wave's first output row

    // ---- Main loads: 18 coalesced f4 row-chunks (1KB/instruction) ----
    f4 X[ROWS + 2];
    #pragma unroll
    for (int k = 0; k < ROWS + 2; ++k) {
        int rr = r0 - 1 + k;
        rr = rr < 0 ? 0 : (rr > Ht - 1 ? Ht - 1 : rr);  // border rows zeroed below
        X[k] = *(const f4*)(x + (size_t)rr * Wd + c);
    }

    // ---- Halo: ONE masked load covers both sides x all 18 window rows ----
    // lane k (k<18): left halo f2 (cols cbase-2,-1) of row r0-1+k
    // lane 32+k:     right halo f2 (cols cbase+256,+257) of row r0-1+k
    f2 hl = {0.f, 0.f};
    {
        const int  hk    = lane & 31;
        const bool left  = lane < 32;
        const bool valid = (hk < ROWS + 2) && (left ? (wc > 0) : (wc < 15));
        if (valid) {
            int rr = r0 - 1 + hk;
            rr = rr < 0 ? 0 : (rr > Ht - 1 ? Ht - 1 : rr);
            const int hc = left ? cbase - 2 : cbase + 256;
            hl = *(const f2*)(x + (size_t)rr * Wd + hc);
        }
    }

    // Pin all loads above this point: prevent the compiler from software-
    // pipelining them down to their consumers (R11 failure mode, VGPR=72).
    __builtin_amdgcn_sched_barrier(0);

    // Per-lane halo t: lane (side*32 + o) holds the t-halo for output row r0+o.
    const float s1x = __shfl_down(hl.x, 1), s2x = __shfl_down(hl.x, 2);
    const float s1y = __shfl_down(hl.y, 1), s2y = __shfl_down(hl.y, 2);
    const float th1x = hl.x + 2.0f * s1x + s2x;   // t1 of halo col 0
    const float th1y = hl.y + 2.0f * s1y + s2y;   // t1 of halo col 1
    const float th2x = hl.x - s2x;                // t2 of halo col 0
    const float th2y = hl.y - s2y;                // t2 of halo col 1

    const float C1  = __uint_as_float(0x3CB851EDu);  // q > C1  <=> sqrt(q) > 0.15f
    const float C2B = __uint_as_float(0x3B23D709u);  // q > C2B <=> sqrt(q) >= 0.05f

    #pragma unroll
    for (int o = 0; o < ROWS; ++o) {
        const int r = r0 + o;
        f4 a = X[o], b = X[o + 1], cc = X[o + 2];

        // Vertical pass for own 4 cols: t1 = a+2b+c (gx), t2 = a-c (gy).
        float t1[4], t2[4];
        #pragma unroll
        for (int j = 0; j < 4; ++j) {
            t1[j] = a[j] + 2.0f * b[j] + cc[j];
            t2[j] = a[j] - cc[j];
        }

        // Halo broadcast: lane 0 wants left (lane o), lane 63 right (lane 32+o).
        const int hidx = (lane == 63) ? 32 + o : o;
        const float b1x = __shfl(th1x, hidx);
        const float b1y = __shfl(th1y, hidx);
        const float b2x = __shfl(th2x, hidx);
        const float b2y = __shfl(th2y, hidx);

        // Neighbor t via shuffle: left lane's cols 2,3 / right lane's cols 0,1.
        float l1a = __shfl_up(t1[2], 1),   l1b = __shfl_up(t1[3], 1);
        float l2a = __shfl_up(t2[2], 1),   l2b = __shfl_up(t2[3], 1);
        float r1a = __shfl_down(t1[0], 1), r1b = __shfl_down(t1[1], 1);
        float r2a = __shfl_down(t2[0], 1), r2b = __shfl_down(t2[1], 1);
        if (lane == 0)  { l1a = b1x; l1b = b1y; l2a = b2x; l2b = b2y; }
        if (lane == 63) { r1a = b1x; r1b = b1y; r2a = b2x; r2b = b2y; }

        // T index k = image col c + (k-2), k = 0..7.
        float T1[8] = {l1a, l1b, t1[0], t1[1], t1[2], t1[3], r1a, r1b};
        float T2[8] = {l2a, l2b, t2[0], t2[1], t2[2], t2[3], r2a, r2b};

        // Squared gradient magnitude q[i] at image col c + (i-1), i = 0..5.
        float q[6];
        #pragma unroll
        for (int i = 0; i < 6; ++i) {
            float gx = T1[i + 2] - T1[i];
            float gy = T2[i] + 2.0f * T2[i + 1] + T2[i + 2];
            q[i] = gx * gx + gy * gy;
        }

        // Hazard net: near-tie q pairs could flip >= after sqrt rounding.
        bool hazard = false;
        #pragma unroll
        for (int i = 0; i < 5; ++i) {
            int d = (int)(__float_as_uint(q[i + 1]) - __float_as_uint(q[i]));
            hazard |= ((unsigned)(d + 8) < 17u);
        }

        float acc[4];
        #pragma unroll
        for (int o2 = 0; o2 < 4; ++o2) {
            float qp = q[o2], qc = q[o2 + 1], qn = q[o2 + 2];
            bool keep = (qc >= qp) && (qc >= qn);
            acc[o2] = (keep && qc > C1) ? 255.0f : 0.0f;
            hazard |= (keep && qc > 0.0f && qc <= C2B);  // pass-through needs sqrt
        }

        if (__any(hazard)) {
            // Exact reference path (rare).
            float m[6];
            #pragma unroll
            for (int i = 0; i < 6; ++i) m[i] = sqrtf(q[i]);
            #pragma unroll
            for (int o2 = 0; o2 < 4; ++o2) {
                float mc = m[o2 + 1];
                bool keep = (mc >= m[o2]) && (mc >= m[o2 + 2]);
                float e = keep ? mc : 0.0f;
                acc[o2] = (e > 0.15f) ? 255.0f : ((e >= 0.05f) ? 0.0f : e);
            }
        }

        // Zero border shell, exactly as the reference.
        if (r == 0 || r == Ht - 1) {
            #pragma unroll
            for (int o2 = 0; o2 < 4; ++o2) acc[o2] = 0.0f;
        }
        if (wc == 0  && lane == 0)  acc[0] = 0.0f;
        if (wc == 15 && lane == 63) acc[3] = 0.0f;

        f4 v = {acc[0], acc[1], acc[2], acc[3]};
        __builtin_nontemporal_store(v, (f4*)(out + (size_t)r * Wd + c));
    }
}

extern "C" void kernel_launch(void* const* d_in, const int* in_sizes, int n_in,
                              void* d_out, int out_size, void* d_ws, size_t ws_size,
                              hipStream_t stream) {
    const float* x = (const float*)d_in[0];
    float* out = (float*)d_out;
    dim3 grid(16, 256);   // 16 col-bands x 256 wave-blocks of 16 rows
    canny_kernel<<<grid, dim3(64), 0, stream>>>(x, out);
}